// Round 5
// baseline (18730.800 us; speedup 1.0000x reference)
//
#include <hip/hip_runtime.h>

#define B_ 16
#define T_ 1024
#define D_ 128
#define H_ 1024
#define O_ 64
#define ALPHA_ 0.1f
#define LEAK_ 0.9f
#define GRID_SCAN 256
#define FLAG_STRIDE 32   // 128B per flag line

typedef float f32x4 __attribute__((ext_vector_type(4)));

// ---------------------------------------------------------------------------
// Kernel 1: P0[b][t][j] = ALPHA * (x[b,t,:] . W_in0[j,:] + b0[j])
// written INTO the states0 region of d_out. The scan reads P0 at (b,t,j) and
// overwrites the same address with tanh(v0) -> no extra buffer needed.
// ---------------------------------------------------------------------------
__global__ __launch_bounds__(256)
void p0_kernel(const float* __restrict__ X, const float* __restrict__ Win0,
               const float* __restrict__ b0, float* __restrict__ P)
{
    __shared__ float Xs[64][68];
    __shared__ float Ws[64][68];
    const int r0 = blockIdx.x * 64;
    const int j0 = blockIdx.y * 64;
    const int tid = threadIdx.x;
    const int ty = tid >> 4, tx = tid & 15;
    float acc[4][4] = {};

    for (int kc = 0; kc < D_; kc += 64) {
        for (int i = tid; i < 64 * 16; i += 256) {   // 64 rows x 16 float4
            int row = i >> 4, c = i & 15;
            *(float4*)&Xs[row][c * 4] =
                *(const float4*)&X[(size_t)(r0 + row) * D_ + kc + c * 4];
            *(float4*)&Ws[row][c * 4] =
                *(const float4*)&Win0[(size_t)(j0 + row) * D_ + kc + c * 4];
        }
        __syncthreads();
        #pragma unroll 4
        for (int k = 0; k < 64; k += 4) {
            float4 xr[4], wv[4];
            #pragma unroll
            for (int i = 0; i < 4; ++i) {
                xr[i] = *(const float4*)&Xs[ty * 4 + i][k];
                wv[i] = *(const float4*)&Ws[tx * 4 + i][k];
            }
            #pragma unroll
            for (int i = 0; i < 4; ++i)
                #pragma unroll
                for (int j = 0; j < 4; ++j) {
                    acc[i][j] = fmaf(xr[i].x, wv[j].x, acc[i][j]);
                    acc[i][j] = fmaf(xr[i].y, wv[j].y, acc[i][j]);
                    acc[i][j] = fmaf(xr[i].z, wv[j].z, acc[i][j]);
                    acc[i][j] = fmaf(xr[i].w, wv[j].w, acc[i][j]);
                }
        }
        __syncthreads();
    }
    #pragma unroll
    for (int i = 0; i < 4; ++i) {
        size_t r = (size_t)(r0 + ty * 4 + i);
        #pragma unroll
        for (int j = 0; j < 4; ++j) {
            int jj = j0 + tx * 4 + j;
            P[r * H_ + jj] = ALPHA_ * (acc[i][j] + b0[jj]);
        }
    }
}

// ---------------------------------------------------------------------------
// Kernel 2: fused 2-layer scan.
//
// Round-5 coherence scheme (R1 structure + cached reads + clean-L2 inv):
//   * state WRITES stay agent-scope relaxed atomic stores (sc1 write-through
//     to the coherent LLC) => the per-XCD L2 NEVER holds dirty scan state,
//     so no writeback fence (wbl2) is ever needed.
//   * state READS are now NORMAL CACHED loads: the 32 blocks on each XCD
//     share one LLC line-fetch per 64B line (~256KB/XCD/iter LLC->L2) and
//     fan out at L2 bandwidth, instead of R1's per-block 16B LLC requests
//     (~64MB/iter of line moves, the dominant ~6us of the 11us iteration).
//   * after each barrier detection: ONE acquire agent fence (buffer_inv =
//     flash invalidate of CLEAN lines, cheap) drops any stale L1/L2 copies.
//     Every state/P0 line is re-read after the fence => always fresh.
//   * flags poll via sc1 bypass loads (unaffected by L2 contents).
//   * the two bg barrier-domains interleave on the same L2s: their line
//     sets are disjoint (different b-rows), so cross-domain invalidates
//     are a perf effect only.
// Barrier (R1-proven): distributed 128B flag lines, tid0 release-store,
// every thread polls one block's flag, then __syncthreads + fence.
// ---------------------------------------------------------------------------
#define LDX4(dst, p) \
    asm volatile("global_load_dwordx4 %0, %1, off" : "=v"(dst) : "v"(p))
#define VMWAIT(n) asm volatile("s_waitcnt vmcnt(" #n ")" ::: "memory")
#define SB0 __builtin_amdgcn_sched_barrier(0)

#define ISSUE_AB(g) do {                                                   \
    const float* pa_ = sa + (size_t)(g) * BT;                              \
    const float* pb_ = sb + (size_t)(g) * BT;                              \
    LDX4(A[g][0], pa_);      LDX4(A[g][1], pa_ + 4);                       \
    LDX4(A[g][2], pa_ + 8);  LDX4(A[g][3], pa_ + 12);                      \
    LDX4(Bv[g][0], pb_);     LDX4(Bv[g][1], pb_ + 4);                      \
    LDX4(Bv[g][2], pb_ + 8); LDX4(Bv[g][3], pb_ + 12);                     \
} while (0)

#define ISSUE_A(g) do {                                                    \
    const float* pa_ = sa + (size_t)(g) * BT;                              \
    LDX4(A[g][0], pa_);      LDX4(A[g][1], pa_ + 4);                       \
    LDX4(A[g][2], pa_ + 8);  LDX4(A[g][3], pa_ + 12);                      \
} while (0)

#define FMA3(g) do {                                                       \
    _Pragma("unroll")                                                      \
    for (int m_ = 0; m_ < 4; ++m_) {                                       \
        _Pragma("unroll")                                                  \
        for (int c_ = 0; c_ < 4; ++c_) {                                   \
            const int kk_ = m_ * 4 + c_;                                   \
            const float xa_ = A[g][m_][c_];                                \
            const float xb_ = Bv[g][m_][c_];                               \
            _Pragma("unroll")                                              \
            for (int j_ = 0; j_ < 4; ++j_) {                               \
                ar0[(g)*4+j_] = fmaf(xa_, wr0[j_][kk_], ar0[(g)*4+j_]);    \
                ai1[(g)*4+j_] = fmaf(xa_, wi1[j_][kk_], ai1[(g)*4+j_]);    \
                ar1[(g)*4+j_] = fmaf(xb_, wr1[j_][kk_], ar1[(g)*4+j_]);    \
            }                                                              \
        }                                                                  \
    }                                                                      \
} while (0)

#define FMA2(g) do {                                                       \
    _Pragma("unroll")                                                      \
    for (int m_ = 0; m_ < 4; ++m_) {                                       \
        _Pragma("unroll")                                                  \
        for (int c_ = 0; c_ < 4; ++c_) {                                   \
            const int kk_ = m_ * 4 + c_;                                   \
            const float xa_ = A[g][m_][c_];                                \
            _Pragma("unroll")                                              \
            for (int j_ = 0; j_ < 4; ++j_) {                               \
                ar0[(g)*4+j_] = fmaf(xa_, wr0[j_][kk_], ar0[(g)*4+j_]);    \
                ai1[(g)*4+j_] = fmaf(xa_, wi1[j_][kk_], ai1[(g)*4+j_]);    \
            }                                                              \
        }                                                                  \
    }                                                                      \
} while (0)

__global__ __launch_bounds__(256, 1)
void scan_kernel(const float* __restrict__ Wr0,
                 const float* __restrict__ Wi1,
                 const float* __restrict__ Wr1,
                 const float* __restrict__ b1,
                 float* __restrict__ states0,   // pre-filled with P0
                 float* __restrict__ states1,
                 unsigned int* __restrict__ flags)
{
    const int tid  = threadIdx.x;
    const int blk  = blockIdx.x;
    const int jg   = blk & 127;     // 128 j-groups of 8
    const int bg   = blk >> 7;      // 2 batch-groups of 8
    const int lane = tid & 63;
    const int w    = tid >> 6;
    const int tile = lane & 3;
    const int kl   = lane >> 2;
    const int bh   = tile & 1;
    const int jh   = tile >> 1;
    const int ks   = w * 16 + kl;   // 0..63
    const int k0   = ks << 4;       // 16-wide k slice
    const int jbase = jg * 8 + jh * 4;
    const int bbase = bg * 8 + bh * 4;
    const size_t BT = (size_t)T_ * H_;

    // ---- pin weights in registers: [4 j][16 k] per matrix ----
    float wr0[4][16], wi1[4][16], wr1[4][16];
    #pragma unroll
    for (int j = 0; j < 4; ++j) {
        const float* p0 = Wr0 + (size_t)(jbase + j) * H_ + k0;
        const float* p1 = Wi1 + (size_t)(jbase + j) * H_ + k0;
        const float* p2 = Wr1 + (size_t)(jbase + j) * H_ + k0;
        #pragma unroll
        for (int m = 0; m < 4; ++m) {
            *(float4*)&wr0[j][m * 4] = ((const float4*)p0)[m];
            *(float4*)&wi1[j][m * 4] = ((const float4*)p1)[m];
            *(float4*)&wr1[j][m * 4] = ((const float4*)p2)[m];
        }
    }

    // ---- owners: tid 0..63 own layer0 outputs, tid 64..127 layer1 ----
    const int o      = tid & 63;
    const int b_loc  = o >> 3, j_loc = o & 7;
    const int gb     = bg * 8 + b_loc;
    const int gj     = jg * 8 + j_loc;
    const int otile  = (j_loc >> 2) * 2 + (b_loc >> 2);
    const int oa     = (b_loc & 3) * 4 + (j_loc & 3);
    float v0 = 0.f, v1 = 0.f;
    const float b1v = b1[gj];

    __shared__ float red[3][4][4][16];   // [matvec][wave][tile][acc]

    unsigned* myflag   = flags + (size_t)blk * FLAG_STRIDE;
    unsigned* pollflag = flags + (size_t)tid * FLAG_STRIDE;

    for (int it = 0; it <= T_; ++it) {
        // early P0 load for layer0 owners (post-fence => fresh). P0 is only
        // overwritten by THIS thread later this same iteration.
        float pval = 0.f;
        size_t oidx0 = 0;
        if (tid < 64 && it < T_) {
            oidx0 = (size_t)gb * BT + (size_t)it * H_ + gj;
            pval = states0[oidx0];
        }

        float ar0[16], ai1[16], ar1[16];
        #pragma unroll
        for (int a = 0; a < 16; ++a) { ar0[a] = 0.f; ai1[a] = 0.f; ar1[a] = 0.f; }

        if (it >= 2) {
            f32x4 A[4][4], Bv[4][4];
            const float* sa = states0 + (size_t)bbase * BT + (size_t)(it - 1) * H_ + k0;
            const float* sb = states1 + (size_t)bbase * BT + (size_t)(it - 2) * H_ + k0;
            // pipeline: 3 groups in flight, peel one per FMA block
            ISSUE_AB(0); ISSUE_AB(1); ISSUE_AB(2);
            VMWAIT(16); SB0;            // group0 landed
            FMA3(0);
            ISSUE_AB(3);
            VMWAIT(16); SB0;            // group1 landed
            FMA3(1);
            VMWAIT(8); SB0;             // group2 landed
            FMA3(2);
            VMWAIT(0); SB0;             // group3 landed
            FMA3(3);
        } else if (it == 1) {
            f32x4 A[4][4];
            const float* sa = states0 + (size_t)bbase * BT + k0;   // t = 0
            ISSUE_A(0); ISSUE_A(1); ISSUE_A(2); ISSUE_A(3);
            VMWAIT(0); SB0;
            FMA2(0); FMA2(1); FMA2(2); FMA2(3);   // ar1 stays 0 (fr1[-1]=0)
        }

        // in-wave reduction over kl (lane bits 2..5)
        #pragma unroll
        for (int mask = 4; mask < 64; mask <<= 1)
            #pragma unroll
            for (int a = 0; a < 16; ++a) {
                ar0[a] += __shfl_xor(ar0[a], mask);
                ai1[a] += __shfl_xor(ai1[a], mask);
                ar1[a] += __shfl_xor(ar1[a], mask);
            }
        if (lane < 4) {
            #pragma unroll
            for (int a = 0; a < 16; ++a) {
                red[0][w][lane][a] = ar0[a];
                red[1][w][lane][a] = ai1[a];
                red[2][w][lane][a] = ar1[a];
            }
        }
        __syncthreads();

        if (tid < 64) {
            if (it < T_) {
                float s = red[0][0][otile][oa] + red[0][1][otile][oa]
                        + red[0][2][otile][oa] + red[0][3][otile][oa];
                v0 = LEAK_ * v0 + pval + ALPHA_ * s;
                float fr = tanhf(v0);
                // write-through to LLC (agent scope): L2 never dirty
                __hip_atomic_store(&states0[oidx0], fr, __ATOMIC_RELAXED,
                                   __HIP_MEMORY_SCOPE_AGENT);
            }
        } else if (tid < 128) {
            if (it >= 1) {
                float s1 = red[1][0][otile][oa] + red[1][1][otile][oa]
                         + red[1][2][otile][oa] + red[1][3][otile][oa];
                float s2 = red[2][0][otile][oa] + red[2][1][otile][oa]
                         + red[2][2][otile][oa] + red[2][3][otile][oa];
                v1 = LEAK_ * v1 + ALPHA_ * (s1 + s2 + b1v);
                float fr = tanhf(v1);
                __hip_atomic_store(&states1[(size_t)gb * BT + (size_t)(it - 1) * H_ + gj],
                                   fr, __ATOMIC_RELAXED, __HIP_MEMORY_SCOPE_AGENT);
            }
        }

        if (it < T_) {
            // ---- grid barrier: distributed flags (R1-proven tail) ----
            __syncthreads();   // all waves' stores drained (vmcnt0 @ barrier)
            const unsigned tgt = (unsigned)(it + 1);
            if (tid == 0) {
                // release: orders the write-through state stores before the
                // flag becomes visible at the LLC.
                __hip_atomic_store(myflag, tgt, __ATOMIC_RELEASE,
                                   __HIP_MEMORY_SCOPE_AGENT);
            }
            // each thread polls one block's flag line (256 distinct lines)
            while (__hip_atomic_load(pollflag, __ATOMIC_RELAXED,
                                     __HIP_MEMORY_SCOPE_AGENT) < tgt)
                __builtin_amdgcn_s_sleep(2);
            __syncthreads();
            // acquire: flash-invalidate CLEAN L1/L2 copies so the next
            // iteration's cached reads refill fresh from the LLC. No dirty
            // lines exist (all scan writes are sc1 write-through) => no
            // writeback cost, just the invalidate.
            __builtin_amdgcn_fence(__ATOMIC_ACQUIRE, "agent");
            SB0;
        }
    }
}

// ---------------------------------------------------------------------------
// Kernel 3: out[r][o] = states1[r,:] . W_out[o,:] + b_out[o],  r = b*T+t
// ---------------------------------------------------------------------------
__global__ __launch_bounds__(256)
void out_kernel(const float* __restrict__ S1, const float* __restrict__ Wout,
                const float* __restrict__ bout, float* __restrict__ Out)
{
    __shared__ float Ss[64][36];
    __shared__ float Ws[64][36];
    const int r0 = blockIdx.x * 64;
    const int tid = threadIdx.x;
    const int ty = tid >> 4, tx = tid & 15;
    float acc[4][4] = {};

    for (int kc = 0; kc < H_; kc += 32) {
        for (int i = tid; i < 64 * 8; i += 256) {   // 64 rows x 8 float4
            int row = i >> 3, c = i & 7;
            *(float4*)&Ss[row][c * 4] =
                *(const float4*)&S1[(size_t)(r0 + row) * H_ + kc + c * 4];
            *(float4*)&Ws[row][c * 4] =
                *(const float4*)&Wout[(size_t)row * H_ + kc + c * 4];
        }
        __syncthreads();
        #pragma unroll 2
        for (int k = 0; k < 32; k += 4) {
            float4 xr[4], wv[4];
            #pragma unroll
            for (int i = 0; i < 4; ++i) {
                xr[i] = *(const float4*)&Ss[ty * 4 + i][k];
                wv[i] = *(const float4*)&Ws[tx * 4 + i][k];
            }
            #pragma unroll
            for (int i = 0; i < 4; ++i)
                #pragma unroll
                for (int j = 0; j < 4; ++j) {
                    acc[i][j] = fmaf(xr[i].x, wv[j].x, acc[i][j]);
                    acc[i][j] = fmaf(xr[i].y, wv[j].y, acc[i][j]);
                    acc[i][j] = fmaf(xr[i].z, wv[j].z, acc[i][j]);
                    acc[i][j] = fmaf(xr[i].w, wv[j].w, acc[i][j]);
                }
        }
        __syncthreads();
    }
    #pragma unroll
    for (int i = 0; i < 4; ++i) {
        size_t r = (size_t)(r0 + ty * 4 + i);
        #pragma unroll
        for (int j = 0; j < 4; ++j) {
            int oo = tx * 4 + j;
            Out[r * O_ + oo] = acc[i][j] + bout[oo];
        }
    }
}

// ---------------------------------------------------------------------------
extern "C" void kernel_launch(void* const* d_in, const int* in_sizes, int n_in,
                              void* d_out, int out_size, void* d_ws, size_t ws_size,
                              hipStream_t stream)
{
    (void)in_sizes; (void)n_in; (void)out_size; (void)ws_size;

    const float* x    = (const float*)d_in[0];
    const float* Win0 = (const float*)d_in[1];
    const float* Wr0  = (const float*)d_in[2];
    const float* b0   = (const float*)d_in[3];
    const float* Wi1  = (const float*)d_in[4];
    const float* Wr1  = (const float*)d_in[5];
    const float* b1   = (const float*)d_in[6];
    const float* Wout = (const float*)d_in[7];
    const float* bout = (const float*)d_in[8];

    float* out     = (float*)d_out;
    float* states0 = out + (size_t)B_ * T_ * O_;
    float* states1 = states0 + (size_t)B_ * T_ * H_;

    unsigned* flags = (unsigned*)d_ws;   // 256 flags, 128B apart = 32KB

    // zero flag lines (ws is poisoned 0xAA before every call)
    hipMemsetAsync(d_ws, 0, GRID_SCAN * FLAG_STRIDE * sizeof(unsigned), stream);

    // P0 -> states0 region
    p0_kernel<<<dim3(B_ * T_ / 64, H_ / 64), 256, 0, stream>>>(x, Win0, b0, states0);

    // fused scan
    scan_kernel<<<dim3(GRID_SCAN), dim3(256), 0, stream>>>(
        Wr0, Wi1, Wr1, b1, states0, states1, flags);

    // readout
    out_kernel<<<dim3(B_ * T_ / 64), 256, 0, stream>>>(states1, Wout, bout, out);
}

// Round 6
// 11159.184 us; speedup vs baseline: 1.6785x; 1.6785x over previous
//
#include <hip/hip_runtime.h>

#define B_ 16
#define T_ 1024
#define D_ 128
#define H_ 1024
#define O_ 64
#define ALPHA_ 0.1f
#define LEAK_ 0.9f
#define GRID_SCAN 256
#define FLAG_STRIDE 32   // 128B per flag line

typedef float f32x4 __attribute__((ext_vector_type(4)));

// ---------------------------------------------------------------------------
// Kernel 1: P0[b][t][j] = ALPHA * (x[b,t,:] . W_in0[j,:] + b0[j])
// written INTO the states0 region of d_out. The scan reads P0 at (b,t,j) and
// overwrites the same address with tanh(v0) -> no extra buffer needed.
// ---------------------------------------------------------------------------
__global__ __launch_bounds__(256)
void p0_kernel(const float* __restrict__ X, const float* __restrict__ Win0,
               const float* __restrict__ b0, float* __restrict__ P)
{
    __shared__ float Xs[64][68];
    __shared__ float Ws[64][68];
    const int r0 = blockIdx.x * 64;
    const int j0 = blockIdx.y * 64;
    const int tid = threadIdx.x;
    const int ty = tid >> 4, tx = tid & 15;
    float acc[4][4] = {};

    for (int kc = 0; kc < D_; kc += 64) {
        for (int i = tid; i < 64 * 16; i += 256) {   // 64 rows x 16 float4
            int row = i >> 4, c = i & 15;
            *(float4*)&Xs[row][c * 4] =
                *(const float4*)&X[(size_t)(r0 + row) * D_ + kc + c * 4];
            *(float4*)&Ws[row][c * 4] =
                *(const float4*)&Win0[(size_t)(j0 + row) * D_ + kc + c * 4];
        }
        __syncthreads();
        #pragma unroll 4
        for (int k = 0; k < 64; k += 4) {
            float4 xr[4], wv[4];
            #pragma unroll
            for (int i = 0; i < 4; ++i) {
                xr[i] = *(const float4*)&Xs[ty * 4 + i][k];
                wv[i] = *(const float4*)&Ws[tx * 4 + i][k];
            }
            #pragma unroll
            for (int i = 0; i < 4; ++i)
                #pragma unroll
                for (int j = 0; j < 4; ++j) {
                    acc[i][j] = fmaf(xr[i].x, wv[j].x, acc[i][j]);
                    acc[i][j] = fmaf(xr[i].y, wv[j].y, acc[i][j]);
                    acc[i][j] = fmaf(xr[i].z, wv[j].z, acc[i][j]);
                    acc[i][j] = fmaf(xr[i].w, wv[j].w, acc[i][j]);
                }
        }
        __syncthreads();
    }
    #pragma unroll
    for (int i = 0; i < 4; ++i) {
        size_t r = (size_t)(r0 + ty * 4 + i);
        #pragma unroll
        for (int j = 0; j < 4; ++j) {
            int jj = j0 + tx * 4 + j;
            P[r * H_ + jj] = ALPHA_ * (acc[i][j] + b0[jj]);
        }
    }
}

// ---------------------------------------------------------------------------
// Kernel 2: fused 2-layer scan — R1 coherence scheme, 16j x 4b block shape.
//
// Coherence (R1-proven, best measured): state writes = agent-scope relaxed
// atomic stores (sc1 write-through to coherent LLC; L2 never dirty => no
// wbl2 fence); state reads = global_load_dwordx4 sc0 sc1 (bypass stale
// L1/L2, read LLC directly => no inv fence). Per-iteration cache fences
// measured at ~7us/iter (R5) — never again. P0 ("pval") is immutable
// during the scan => regular cached load.
//
// Round-6 reshape: blocks go 8j x 8b -> 16j x 4b. Request arithmetic:
// chip-wide LLC reads = (rows per block) x (j-group replicas) is invariant
// in FLOPs but reads HALVE (4 rows x 2 states x 4KB = 32KB/block, 8MB/iter
// vs 16MB), TA same-address merge goes 2-way -> 4-way (4 jq lanes share
// each 16B), and barrier domains shrink 128 -> 64 blocks (4 independent
// bg domains). Weights/thread stay 192 floats; FMA count, shuffle masks,
// accumulator shape, and the R1 barrier tail are unchanged.
// ---------------------------------------------------------------------------
#define LDX4(dst, p) \
    asm volatile("global_load_dwordx4 %0, %1, off sc0 sc1" : "=v"(dst) : "v"(p))
#define VMWAIT(n) asm volatile("s_waitcnt vmcnt(" #n ")" ::: "memory")
#define SB0 __builtin_amdgcn_sched_barrier(0)

#define ISSUE_AB(g) do {                                                   \
    const float* pa_ = sa + (size_t)(g) * BT;                              \
    const float* pb_ = sb + (size_t)(g) * BT;                              \
    LDX4(A[g][0], pa_);      LDX4(A[g][1], pa_ + 4);                       \
    LDX4(A[g][2], pa_ + 8);  LDX4(A[g][3], pa_ + 12);                      \
    LDX4(Bv[g][0], pb_);     LDX4(Bv[g][1], pb_ + 4);                      \
    LDX4(Bv[g][2], pb_ + 8); LDX4(Bv[g][3], pb_ + 12);                     \
} while (0)

#define ISSUE_A(g) do {                                                    \
    const float* pa_ = sa + (size_t)(g) * BT;                              \
    LDX4(A[g][0], pa_);      LDX4(A[g][1], pa_ + 4);                       \
    LDX4(A[g][2], pa_ + 8);  LDX4(A[g][3], pa_ + 12);                      \
} while (0)

#define FMA3(g) do {                                                       \
    _Pragma("unroll")                                                      \
    for (int m_ = 0; m_ < 4; ++m_) {                                       \
        _Pragma("unroll")                                                  \
        for (int c_ = 0; c_ < 4; ++c_) {                                   \
            const int kk_ = m_ * 4 + c_;                                   \
            const float xa_ = A[g][m_][c_];                                \
            const float xb_ = Bv[g][m_][c_];                               \
            _Pragma("unroll")                                              \
            for (int j_ = 0; j_ < 4; ++j_) {                               \
                ar0[(g)*4+j_] = fmaf(xa_, wr0[j_][kk_], ar0[(g)*4+j_]);    \
                ai1[(g)*4+j_] = fmaf(xa_, wi1[j_][kk_], ai1[(g)*4+j_]);    \
                ar1[(g)*4+j_] = fmaf(xb_, wr1[j_][kk_], ar1[(g)*4+j_]);    \
            }                                                              \
        }                                                                  \
    }                                                                      \
} while (0)

#define FMA2(g) do {                                                       \
    _Pragma("unroll")                                                      \
    for (int m_ = 0; m_ < 4; ++m_) {                                       \
        _Pragma("unroll")                                                  \
        for (int c_ = 0; c_ < 4; ++c_) {                                   \
            const int kk_ = m_ * 4 + c_;                                   \
            const float xa_ = A[g][m_][c_];                                \
            _Pragma("unroll")                                              \
            for (int j_ = 0; j_ < 4; ++j_) {                               \
                ar0[(g)*4+j_] = fmaf(xa_, wr0[j_][kk_], ar0[(g)*4+j_]);    \
                ai1[(g)*4+j_] = fmaf(xa_, wi1[j_][kk_], ai1[(g)*4+j_]);    \
            }                                                              \
        }                                                                  \
    }                                                                      \
} while (0)

__global__ __launch_bounds__(256, 1)
void scan_kernel(const float* __restrict__ Wr0,
                 const float* __restrict__ Wi1,
                 const float* __restrict__ Wr1,
                 const float* __restrict__ b1,
                 float* __restrict__ states0,   // pre-filled with P0
                 float* __restrict__ states1,
                 unsigned int* __restrict__ flags)
{
    const int tid  = threadIdx.x;
    const int blk  = blockIdx.x;
    const int jg   = blk & 63;      // 64 j-groups of 16
    const int bg   = blk >> 6;      // 4 batch-groups of 4
    const int lane = tid & 63;
    const int w    = tid >> 6;
    const int jq   = lane & 3;      // j-quad within the 16-j group
    const int kl   = lane >> 2;     // 16 k-slices per wave
    const int ks   = w * 16 + kl;   // 0..63
    const int k0   = ks << 4;       // 16-wide k slice
    const int jbase = jg * 16 + jq * 4;
    const size_t BT = (size_t)T_ * H_;

    // ---- pin weights in registers: [4 j][16 k] per matrix ----
    float wr0[4][16], wi1[4][16], wr1[4][16];
    #pragma unroll
    for (int j = 0; j < 4; ++j) {
        const float* p0 = Wr0 + (size_t)(jbase + j) * H_ + k0;
        const float* p1 = Wi1 + (size_t)(jbase + j) * H_ + k0;
        const float* p2 = Wr1 + (size_t)(jbase + j) * H_ + k0;
        #pragma unroll
        for (int m = 0; m < 4; ++m) {
            *(float4*)&wr0[j][m * 4] = ((const float4*)p0)[m];
            *(float4*)&wi1[j][m * 4] = ((const float4*)p1)[m];
            *(float4*)&wr1[j][m * 4] = ((const float4*)p2)[m];
        }
    }

    // ---- owners: tid 0..63 own layer0 outputs (4b x 16j), 64..127 layer1 ----
    const int o      = tid & 63;
    const int b_loc  = o >> 4, j_loc = o & 15;
    const int gb     = bg * 4 + b_loc;
    const int gj     = jg * 16 + j_loc;
    const int otile  = j_loc >> 2;                 // jq of this output
    const int oa     = b_loc * 4 + (j_loc & 3);    // acc index g*4+jj
    float v0 = 0.f, v1 = 0.f;
    const float b1v = b1[gj];

    __shared__ float red[3][4][4][16];   // [matvec][wave][jq][acc]

    unsigned* myflag   = flags + (size_t)blk * FLAG_STRIDE;
    // poll own bg-domain only (64 blocks); 4 threads/block share each flag
    unsigned* pollflag = flags + (size_t)(bg * 64 + (tid & 63)) * FLAG_STRIDE;

    for (int it = 0; it <= T_; ++it) {
        // early P0 load for layer0 owners. P0 is written before the scan
        // launches and only overwritten by THIS thread later this iteration,
        // so a regular cached load is safe (never stale).
        float pval = 0.f;
        size_t oidx0 = 0;
        if (tid < 64 && it < T_) {
            oidx0 = (size_t)gb * BT + (size_t)it * H_ + gj;
            pval = states0[oidx0];
        }

        float ar0[16], ai1[16], ar1[16];
        #pragma unroll
        for (int a = 0; a < 16; ++a) { ar0[a] = 0.f; ai1[a] = 0.f; ar1[a] = 0.f; }

        if (it >= 2) {
            f32x4 A[4][4], Bv[4][4];
            const float* sa = states0 + (size_t)(bg * 4) * BT + (size_t)(it - 1) * H_ + k0;
            const float* sb = states1 + (size_t)(bg * 4) * BT + (size_t)(it - 2) * H_ + k0;
            // pipeline: 3 groups in flight, peel one per FMA block
            ISSUE_AB(0); ISSUE_AB(1); ISSUE_AB(2);
            VMWAIT(16); SB0;            // group0 landed
            FMA3(0);
            ISSUE_AB(3);
            VMWAIT(16); SB0;            // group1 landed
            FMA3(1);
            VMWAIT(8); SB0;             // group2 landed
            FMA3(2);
            VMWAIT(0); SB0;             // group3 landed
            FMA3(3);
        } else if (it == 1) {
            f32x4 A[4][4];
            const float* sa = states0 + (size_t)(bg * 4) * BT + k0;   // t = 0
            ISSUE_A(0); ISSUE_A(1); ISSUE_A(2); ISSUE_A(3);
            VMWAIT(0); SB0;
            FMA2(0); FMA2(1); FMA2(2); FMA2(3);   // ar1 stays 0 (fr1[-1]=0)
        }

        // in-wave reduction over kl (lane bits 2..5)
        #pragma unroll
        for (int mask = 4; mask < 64; mask <<= 1)
            #pragma unroll
            for (int a = 0; a < 16; ++a) {
                ar0[a] += __shfl_xor(ar0[a], mask);
                ai1[a] += __shfl_xor(ai1[a], mask);
                ar1[a] += __shfl_xor(ar1[a], mask);
            }
        if (lane < 4) {                  // kl==0 lanes, one per jq
            #pragma unroll
            for (int a = 0; a < 16; ++a) {
                red[0][w][lane][a] = ar0[a];
                red[1][w][lane][a] = ai1[a];
                red[2][w][lane][a] = ar1[a];
            }
        }
        __syncthreads();

        if (tid < 64) {
            if (it < T_) {
                float s = red[0][0][otile][oa] + red[0][1][otile][oa]
                        + red[0][2][otile][oa] + red[0][3][otile][oa];
                v0 = LEAK_ * v0 + pval + ALPHA_ * s;
                float fr = tanhf(v0);
                // write-through to LLC (agent scope): L2 never dirty
                __hip_atomic_store(&states0[oidx0], fr, __ATOMIC_RELAXED,
                                   __HIP_MEMORY_SCOPE_AGENT);
            }
        } else if (tid < 128) {
            if (it >= 1) {
                float s1 = red[1][0][otile][oa] + red[1][1][otile][oa]
                         + red[1][2][otile][oa] + red[1][3][otile][oa];
                float s2 = red[2][0][otile][oa] + red[2][1][otile][oa]
                         + red[2][2][otile][oa] + red[2][3][otile][oa];
                v1 = LEAK_ * v1 + ALPHA_ * (s1 + s2 + b1v);
                float fr = tanhf(v1);
                __hip_atomic_store(&states1[(size_t)gb * BT + (size_t)(it - 1) * H_ + gj],
                                   fr, __ATOMIC_RELAXED, __HIP_MEMORY_SCOPE_AGENT);
            }
        }

        if (it < T_) {
            // ---- grid barrier: distributed flags, same-bg domain (64 blks),
            // ---- R1-proven tail ----
            __syncthreads();   // all waves' stores drained (vmcnt0 @ barrier)
            const unsigned tgt = (unsigned)(it + 1);
            if (tid == 0) {
                // release: orders the write-through state stores before the
                // flag becomes visible at the LLC.
                __hip_atomic_store(myflag, tgt, __ATOMIC_RELEASE,
                                   __HIP_MEMORY_SCOPE_AGENT);
            }
            // each thread polls one domain flag line (64 distinct lines)
            while (__hip_atomic_load(pollflag, __ATOMIC_RELAXED,
                                     __HIP_MEMORY_SCOPE_AGENT) < tgt)
                __builtin_amdgcn_s_sleep(2);
            __syncthreads();
            // no acquire fence: next iteration's state reads bypass L1/L2
            // (sc0 sc1) and read the coherent LLC directly.
        }
    }
}

// ---------------------------------------------------------------------------
// Kernel 3: out[r][o] = states1[r,:] . W_out[o,:] + b_out[o],  r = b*T+t
// ---------------------------------------------------------------------------
__global__ __launch_bounds__(256)
void out_kernel(const float* __restrict__ S1, const float* __restrict__ Wout,
                const float* __restrict__ bout, float* __restrict__ Out)
{
    __shared__ float Ss[64][36];
    __shared__ float Ws[64][36];
    const int r0 = blockIdx.x * 64;
    const int tid = threadIdx.x;
    const int ty = tid >> 4, tx = tid & 15;
    float acc[4][4] = {};

    for (int kc = 0; kc < H_; kc += 32) {
        for (int i = tid; i < 64 * 8; i += 256) {   // 64 rows x 8 float4
            int row = i >> 3, c = i & 7;
            *(float4*)&Ss[row][c * 4] =
                *(const float4*)&S1[(size_t)(r0 + row) * H_ + kc + c * 4];
            *(float4*)&Ws[row][c * 4] =
                *(const float4*)&Wout[(size_t)row * H_ + kc + c * 4];
        }
        __syncthreads();
        #pragma unroll 2
        for (int k = 0; k < 32; k += 4) {
            float4 xr[4], wv[4];
            #pragma unroll
            for (int i = 0; i < 4; ++i) {
                xr[i] = *(const float4*)&Ss[ty * 4 + i][k];
                wv[i] = *(const float4*)&Ws[tx * 4 + i][k];
            }
            #pragma unroll
            for (int i = 0; i < 4; ++i)
                #pragma unroll
                for (int j = 0; j < 4; ++j) {
                    acc[i][j] = fmaf(xr[i].x, wv[j].x, acc[i][j]);
                    acc[i][j] = fmaf(xr[i].y, wv[j].y, acc[i][j]);
                    acc[i][j] = fmaf(xr[i].z, wv[j].z, acc[i][j]);
                    acc[i][j] = fmaf(xr[i].w, wv[j].w, acc[i][j]);
                }
        }
        __syncthreads();
    }
    #pragma unroll
    for (int i = 0; i < 4; ++i) {
        size_t r = (size_t)(r0 + ty * 4 + i);
        #pragma unroll
        for (int j = 0; j < 4; ++j) {
            int oo = tx * 4 + j;
            Out[r * O_ + oo] = acc[i][j] + bout[oo];
        }
    }
}

// ---------------------------------------------------------------------------
extern "C" void kernel_launch(void* const* d_in, const int* in_sizes, int n_in,
                              void* d_out, int out_size, void* d_ws, size_t ws_size,
                              hipStream_t stream)
{
    (void)in_sizes; (void)n_in; (void)out_size; (void)ws_size;

    const float* x    = (const float*)d_in[0];
    const float* Win0 = (const float*)d_in[1];
    const float* Wr0  = (const float*)d_in[2];
    const float* b0   = (const float*)d_in[3];
    const float* Wi1  = (const float*)d_in[4];
    const float* Wr1  = (const float*)d_in[5];
    const float* b1   = (const float*)d_in[6];
    const float* Wout = (const float*)d_in[7];
    const float* bout = (const float*)d_in[8];

    float* out     = (float*)d_out;
    float* states0 = out + (size_t)B_ * T_ * O_;
    float* states1 = states0 + (size_t)B_ * T_ * H_;

    unsigned* flags = (unsigned*)d_ws;   // 256 flags, 128B apart = 32KB

    // zero flag lines (ws is poisoned 0xAA before every call)
    hipMemsetAsync(d_ws, 0, GRID_SCAN * FLAG_STRIDE * sizeof(unsigned), stream);

    // P0 -> states0 region
    p0_kernel<<<dim3(B_ * T_ / 64, H_ / 64), 256, 0, stream>>>(x, Win0, b0, states0);

    // fused scan
    scan_kernel<<<dim3(GRID_SCAN), dim3(256), 0, stream>>>(
        Wr0, Wi1, Wr1, b1, states0, states1, flags);

    // readout
    out_kernel<<<dim3(B_ * T_ / 64), 256, 0, stream>>>(states1, Wout, bout, out);
}

// Round 7
// 9281.297 us; speedup vs baseline: 2.0181x; 1.2023x over previous
//
#include <hip/hip_runtime.h>

#define B_ 16
#define T_ 1024
#define D_ 128
#define H_ 1024
#define O_ 64
#define ALPHA_ 0.1f
#define LEAK_ 0.9f
#define GRID_SCAN 256
#define FLAG_STRIDE 32   // 128B per flag line

typedef float f32x4 __attribute__((ext_vector_type(4)));

// ---------------------------------------------------------------------------
// Kernel 1: P0[b][t][j] = ALPHA * (x[b,t,:] . W_in0[j,:] + b0[j])
// written INTO the states0 region of d_out. The scan reads P0 at (b,t,j) and
// overwrites the same address with tanh(v0) -> no extra buffer needed.
// ---------------------------------------------------------------------------
__global__ __launch_bounds__(256)
void p0_kernel(const float* __restrict__ X, const float* __restrict__ Win0,
               const float* __restrict__ b0, float* __restrict__ P)
{
    __shared__ float Xs[64][68];
    __shared__ float Ws[64][68];
    const int r0 = blockIdx.x * 64;
    const int j0 = blockIdx.y * 64;
    const int tid = threadIdx.x;
    const int ty = tid >> 4, tx = tid & 15;
    float acc[4][4] = {};

    for (int kc = 0; kc < D_; kc += 64) {
        for (int i = tid; i < 64 * 16; i += 256) {   // 64 rows x 16 float4
            int row = i >> 4, c = i & 15;
            *(float4*)&Xs[row][c * 4] =
                *(const float4*)&X[(size_t)(r0 + row) * D_ + kc + c * 4];
            *(float4*)&Ws[row][c * 4] =
                *(const float4*)&Win0[(size_t)(j0 + row) * D_ + kc + c * 4];
        }
        __syncthreads();
        #pragma unroll 4
        for (int k = 0; k < 64; k += 4) {
            float4 xr[4], wv[4];
            #pragma unroll
            for (int i = 0; i < 4; ++i) {
                xr[i] = *(const float4*)&Xs[ty * 4 + i][k];
                wv[i] = *(const float4*)&Ws[tx * 4 + i][k];
            }
            #pragma unroll
            for (int i = 0; i < 4; ++i)
                #pragma unroll
                for (int j = 0; j < 4; ++j) {
                    acc[i][j] = fmaf(xr[i].x, wv[j].x, acc[i][j]);
                    acc[i][j] = fmaf(xr[i].y, wv[j].y, acc[i][j]);
                    acc[i][j] = fmaf(xr[i].z, wv[j].z, acc[i][j]);
                    acc[i][j] = fmaf(xr[i].w, wv[j].w, acc[i][j]);
                }
        }
        __syncthreads();
    }
    #pragma unroll
    for (int i = 0; i < 4; ++i) {
        size_t r = (size_t)(r0 + ty * 4 + i);
        #pragma unroll
        for (int j = 0; j < 4; ++j) {
            int jj = j0 + tx * 4 + j;
            P[r * H_ + jj] = ALPHA_ * (acc[i][j] + b0[jj]);
        }
    }
}

// ---------------------------------------------------------------------------
// Kernel 2: fused 2-layer scan — CACHED consumer loads, zero fences.
//
// Coherence proof (round 7):
//   * state WRITES: agent-scope relaxed atomic stores = sc1 write-through to
//     the memory-side LLC. L2 never holds dirty scan state.
//   * each state row states*[b][t][:] is written exactly once (iter t) and
//     consumer-read exactly once (iter t+1 / t+2). A stale L1/L2 copy can
//     only exist if the line was cached BEFORE its fr-write. The only such
//     path was pval (cached P0 read of line (b,t) at iter t, earlier than
//     that line's fr-write) -> pval is now an sc1 BYPASS load.
//   * therefore the bulk consumer loads are PLAIN CACHED loads: the line is
//     first cached strictly after its sc1 write landed in the LLC => always
//     fresh => no buffer_inv, no wbl2, ever. (R5 measured per-iter inv at
//     ~7us — this gets L2 amortization without it.)
//   * XCD swizzle: bg-domain d lives on XCDs {2d,2d+1} => each LLC line
//     fill is shared by the 32 same-bg blocks of that XCD; most loads
//     become L1/L2 hits instead of ~700-cycle LLC round-trips (the exposed
//     latency that R4/R6 showed dominates the 11us iteration).
// Barrier (R6-proven): distributed 128B flag lines, per-bg domains (64
// blocks), tid0 release-store, each thread polls one domain flag.
// ---------------------------------------------------------------------------
#define LDX4(dst, p) \
    asm volatile("global_load_dwordx4 %0, %1, off" : "=v"(dst) : "v"(p))
#define LDSC(dst, p) \
    asm volatile("global_load_dword %0, %1, off sc0 sc1" : "=v"(dst) : "v"(p))
#define VMWAIT(n) asm volatile("s_waitcnt vmcnt(" #n ")" ::: "memory")
#define SB0 __builtin_amdgcn_sched_barrier(0)

#define ISSUE_AB(g) do {                                                   \
    const float* pa_ = sa + (size_t)(g) * BT;                              \
    const float* pb_ = sb + (size_t)(g) * BT;                              \
    LDX4(A[g][0], pa_);      LDX4(A[g][1], pa_ + 4);                       \
    LDX4(A[g][2], pa_ + 8);  LDX4(A[g][3], pa_ + 12);                      \
    LDX4(Bv[g][0], pb_);     LDX4(Bv[g][1], pb_ + 4);                      \
    LDX4(Bv[g][2], pb_ + 8); LDX4(Bv[g][3], pb_ + 12);                     \
} while (0)

#define ISSUE_A(g) do {                                                    \
    const float* pa_ = sa + (size_t)(g) * BT;                              \
    LDX4(A[g][0], pa_);      LDX4(A[g][1], pa_ + 4);                       \
    LDX4(A[g][2], pa_ + 8);  LDX4(A[g][3], pa_ + 12);                      \
} while (0)

#define FMA3(g) do {                                                       \
    _Pragma("unroll")                                                      \
    for (int m_ = 0; m_ < 4; ++m_) {                                       \
        _Pragma("unroll")                                                  \
        for (int c_ = 0; c_ < 4; ++c_) {                                   \
            const int kk_ = m_ * 4 + c_;                                   \
            const float xa_ = A[g][m_][c_];                                \
            const float xb_ = Bv[g][m_][c_];                               \
            _Pragma("unroll")                                              \
            for (int j_ = 0; j_ < 4; ++j_) {                               \
                ar0[(g)*4+j_] = fmaf(xa_, wr0[j_][kk_], ar0[(g)*4+j_]);    \
                ai1[(g)*4+j_] = fmaf(xa_, wi1[j_][kk_], ai1[(g)*4+j_]);    \
                ar1[(g)*4+j_] = fmaf(xb_, wr1[j_][kk_], ar1[(g)*4+j_]);    \
            }                                                              \
        }                                                                  \
    }                                                                      \
} while (0)

#define FMA2(g) do {                                                       \
    _Pragma("unroll")                                                      \
    for (int m_ = 0; m_ < 4; ++m_) {                                       \
        _Pragma("unroll")                                                  \
        for (int c_ = 0; c_ < 4; ++c_) {                                   \
            const int kk_ = m_ * 4 + c_;                                   \
            const float xa_ = A[g][m_][c_];                                \
            _Pragma("unroll")                                              \
            for (int j_ = 0; j_ < 4; ++j_) {                               \
                ar0[(g)*4+j_] = fmaf(xa_, wr0[j_][kk_], ar0[(g)*4+j_]);    \
                ai1[(g)*4+j_] = fmaf(xa_, wi1[j_][kk_], ai1[(g)*4+j_]);    \
            }                                                              \
        }                                                                  \
    }                                                                      \
} while (0)

__global__ __launch_bounds__(256, 1)
void scan_kernel(const float* __restrict__ Wr0,
                 const float* __restrict__ Wi1,
                 const float* __restrict__ Wr1,
                 const float* __restrict__ b1,
                 float* __restrict__ states0,   // pre-filled with P0
                 float* __restrict__ states1,
                 unsigned int* __restrict__ flags)
{
    const int tid  = threadIdx.x;
    // ---- XCD-aware logical id: bg-domain d -> XCDs {2d, 2d+1} ----
    // dispatch maps block -> XCD as blk % 8 (round-robin over 8 XCDs)
    const int xcd  = blockIdx.x & 7;
    const int slot = blockIdx.x >> 3;
    const int bg   = xcd >> 1;               // 4 batch-groups of 4
    const int jg   = slot * 2 + (xcd & 1);   // 64 j-groups of 16
    const int lid  = bg * 64 + jg;           // logical block id (flag index)
    const int lane = tid & 63;
    const int w    = tid >> 6;
    const int jq   = lane & 3;      // j-quad within the 16-j group
    const int kl   = lane >> 2;     // 16 k-slices per wave
    const int ks   = w * 16 + kl;   // 0..63
    const int k0   = ks << 4;       // 16-wide k slice
    const int jbase = jg * 16 + jq * 4;
    const size_t BT = (size_t)T_ * H_;

    // ---- pin weights in registers: [4 j][16 k] per matrix ----
    float wr0[4][16], wi1[4][16], wr1[4][16];
    #pragma unroll
    for (int j = 0; j < 4; ++j) {
        const float* p0 = Wr0 + (size_t)(jbase + j) * H_ + k0;
        const float* p1 = Wi1 + (size_t)(jbase + j) * H_ + k0;
        const float* p2 = Wr1 + (size_t)(jbase + j) * H_ + k0;
        #pragma unroll
        for (int m = 0; m < 4; ++m) {
            *(float4*)&wr0[j][m * 4] = ((const float4*)p0)[m];
            *(float4*)&wi1[j][m * 4] = ((const float4*)p1)[m];
            *(float4*)&wr1[j][m * 4] = ((const float4*)p2)[m];
        }
    }

    // ---- owners: tid 0..63 own layer0 outputs (4b x 16j), 64..127 layer1 ----
    const int o      = tid & 63;
    const int b_loc  = o >> 4, j_loc = o & 15;
    const int gb     = bg * 4 + b_loc;
    const int gj     = jg * 16 + j_loc;
    const int otile  = j_loc >> 2;                 // jq of this output
    const int oa     = b_loc * 4 + (j_loc & 3);    // acc index g*4+jj
    float v0 = 0.f, v1 = 0.f;
    const float b1v = b1[gj];

    __shared__ float red[3][4][4][16];   // [matvec][wave][jq][acc]

    unsigned* myflag   = flags + (size_t)lid * FLAG_STRIDE;
    // poll own bg-domain only (64 blocks); 4 threads/block share each flag
    unsigned* pollflag = flags + (size_t)(bg * 64 + (tid & 63)) * FLAG_STRIDE;

    for (int it = 0; it <= T_; ++it) {
        // early P0 load for layer0 owners — sc1 BYPASS so P0 lines are never
        // pre-cached (they'd go stale when fr overwrites them; see header).
        float pval = 0.f;
        size_t oidx0 = 0;
        if (tid < 64 && it < T_) {
            oidx0 = (size_t)gb * BT + (size_t)it * H_ + gj;
            LDSC(pval, states0 + oidx0);
        }

        float ar0[16], ai1[16], ar1[16];
        #pragma unroll
        for (int a = 0; a < 16; ++a) { ar0[a] = 0.f; ai1[a] = 0.f; ar1[a] = 0.f; }

        if (it >= 2) {
            f32x4 A[4][4], Bv[4][4];
            const float* sa = states0 + (size_t)(bg * 4) * BT + (size_t)(it - 1) * H_ + k0;
            const float* sb = states1 + (size_t)(bg * 4) * BT + (size_t)(it - 2) * H_ + k0;
            // pipeline: 3 groups in flight, peel one per FMA block.
            // (wave0 carries +1 outstanding pval; vmcnt(16) still completes
            // at least all of group0, vmcnt counts verified for both cases)
            ISSUE_AB(0); ISSUE_AB(1); ISSUE_AB(2);
            VMWAIT(16); SB0;            // group0 landed
            FMA3(0);
            ISSUE_AB(3);
            VMWAIT(16); SB0;            // group1 landed
            FMA3(1);
            VMWAIT(8); SB0;             // group2 landed
            FMA3(2);
            VMWAIT(0); SB0;             // group3 + pval landed
            FMA3(3);
        } else if (it == 1) {
            f32x4 A[4][4];
            const float* sa = states0 + (size_t)(bg * 4) * BT + k0;   // t = 0
            ISSUE_A(0); ISSUE_A(1); ISSUE_A(2); ISSUE_A(3);
            VMWAIT(0); SB0;
            FMA2(0); FMA2(1); FMA2(2); FMA2(3);   // ar1 stays 0 (fr1[-1]=0)
        }

        // in-wave reduction over kl (lane bits 2..5)
        #pragma unroll
        for (int mask = 4; mask < 64; mask <<= 1)
            #pragma unroll
            for (int a = 0; a < 16; ++a) {
                ar0[a] += __shfl_xor(ar0[a], mask);
                ai1[a] += __shfl_xor(ai1[a], mask);
                ar1[a] += __shfl_xor(ar1[a], mask);
            }
        if (lane < 4) {                  // kl==0 lanes, one per jq
            #pragma unroll
            for (int a = 0; a < 16; ++a) {
                red[0][w][lane][a] = ar0[a];
                red[1][w][lane][a] = ai1[a];
                red[2][w][lane][a] = ar1[a];
            }
        }
        VMWAIT(0); SB0;                  // pval guaranteed resident (it==0 path)
        __syncthreads();

        if (tid < 64) {
            if (it < T_) {
                float s = red[0][0][otile][oa] + red[0][1][otile][oa]
                        + red[0][2][otile][oa] + red[0][3][otile][oa];
                v0 = LEAK_ * v0 + pval + ALPHA_ * s;
                float fr = tanhf(v0);
                // write-through to LLC (agent scope): L2 never dirty
                __hip_atomic_store(&states0[oidx0], fr, __ATOMIC_RELAXED,
                                   __HIP_MEMORY_SCOPE_AGENT);
            }
        } else if (tid < 128) {
            if (it >= 1) {
                float s1 = red[1][0][otile][oa] + red[1][1][otile][oa]
                         + red[1][2][otile][oa] + red[1][3][otile][oa];
                float s2 = red[2][0][otile][oa] + red[2][1][otile][oa]
                         + red[2][2][otile][oa] + red[2][3][otile][oa];
                v1 = LEAK_ * v1 + ALPHA_ * (s1 + s2 + b1v);
                float fr = tanhf(v1);
                __hip_atomic_store(&states1[(size_t)gb * BT + (size_t)(it - 1) * H_ + gj],
                                   fr, __ATOMIC_RELAXED, __HIP_MEMORY_SCOPE_AGENT);
            }
        }

        if (it < T_) {
            // ---- grid barrier: distributed flags, same-bg domain (64 blks) ----
            __syncthreads();   // all waves' stores drained (vmcnt0 @ barrier)
            const unsigned tgt = (unsigned)(it + 1);
            if (tid == 0) {
                // release: orders the write-through state stores before the
                // flag becomes visible at the LLC.
                __hip_atomic_store(myflag, tgt, __ATOMIC_RELEASE,
                                   __HIP_MEMORY_SCOPE_AGENT);
            }
            // each thread polls one domain flag line (64 distinct lines)
            while (__hip_atomic_load(pollflag, __ATOMIC_RELAXED,
                                     __HIP_MEMORY_SCOPE_AGENT) < tgt)
                __builtin_amdgcn_s_sleep(2);
            __syncthreads();
            // no acquire fence: every state line is first cached AFTER its
            // sc1 write-through landed in the LLC (see header proof).
        }
    }
}

// ---------------------------------------------------------------------------
// Kernel 3: out[r][o] = states1[r,:] . W_out[o,:] + b_out[o],  r = b*T+t
// ---------------------------------------------------------------------------
__global__ __launch_bounds__(256)
void out_kernel(const float* __restrict__ S1, const float* __restrict__ Wout,
                const float* __restrict__ bout, float* __restrict__ Out)
{
    __shared__ float Ss[64][36];
    __shared__ float Ws[64][36];
    const int r0 = blockIdx.x * 64;
    const int tid = threadIdx.x;
    const int ty = tid >> 4, tx = tid & 15;
    float acc[4][4] = {};

    for (int kc = 0; kc < H_; kc += 32) {
        for (int i = tid; i < 64 * 8; i += 256) {   // 64 rows x 8 float4
            int row = i >> 3, c = i & 7;
            *(float4*)&Ss[row][c * 4] =
                *(const float4*)&S1[(size_t)(r0 + row) * H_ + kc + c * 4];
            *(float4*)&Ws[row][c * 4] =
                *(const float4*)&Wout[(size_t)row * H_ + kc + c * 4];
        }
        __syncthreads();
        #pragma unroll 2
        for (int k = 0; k < 32; k += 4) {
            float4 xr[4], wv[4];
            #pragma unroll
            for (int i = 0; i < 4; ++i) {
                xr[i] = *(const float4*)&Ss[ty * 4 + i][k];
                wv[i] = *(const float4*)&Ws[tx * 4 + i][k];
            }
            #pragma unroll
            for (int i = 0; i < 4; ++i)
                #pragma unroll
                for (int j = 0; j < 4; ++j) {
                    acc[i][j] = fmaf(xr[i].x, wv[j].x, acc[i][j]);
                    acc[i][j] = fmaf(xr[i].y, wv[j].y, acc[i][j]);
                    acc[i][j] = fmaf(xr[i].z, wv[j].z, acc[i][j]);
                    acc[i][j] = fmaf(xr[i].w, wv[j].w, acc[i][j]);
                }
        }
        __syncthreads();
    }
    #pragma unroll
    for (int i = 0; i < 4; ++i) {
        size_t r = (size_t)(r0 + ty * 4 + i);
        #pragma unroll
        for (int j = 0; j < 4; ++j) {
            int oo = tx * 4 + j;
            Out[r * O_ + oo] = acc[i][j] + bout[oo];
        }
    }
}

// ---------------------------------------------------------------------------
extern "C" void kernel_launch(void* const* d_in, const int* in_sizes, int n_in,
                              void* d_out, int out_size, void* d_ws, size_t ws_size,
                              hipStream_t stream)
{
    (void)in_sizes; (void)n_in; (void)out_size; (void)ws_size;

    const float* x    = (const float*)d_in[0];
    const float* Win0 = (const float*)d_in[1];
    const float* Wr0  = (const float*)d_in[2];
    const float* b0   = (const float*)d_in[3];
    const float* Wi1  = (const float*)d_in[4];
    const float* Wr1  = (const float*)d_in[5];
    const float* b1   = (const float*)d_in[6];
    const float* Wout = (const float*)d_in[7];
    const float* bout = (const float*)d_in[8];

    float* out     = (float*)d_out;
    float* states0 = out + (size_t)B_ * T_ * O_;
    float* states1 = states0 + (size_t)B_ * T_ * H_;

    unsigned* flags = (unsigned*)d_ws;   // 256 flags, 128B apart = 32KB

    // zero flag lines (ws is poisoned 0xAA before every call)
    hipMemsetAsync(d_ws, 0, GRID_SCAN * FLAG_STRIDE * sizeof(unsigned), stream);

    // P0 -> states0 region
    p0_kernel<<<dim3(B_ * T_ / 64, H_ / 64), 256, 0, stream>>>(x, Win0, b0, states0);

    // fused scan
    scan_kernel<<<dim3(GRID_SCAN), dim3(256), 0, stream>>>(
        Wr0, Wi1, Wr1, b1, states0, states1, flags);

    // readout
    out_kernel<<<dim3(B_ * T_ / 64), 256, 0, stream>>>(states1, Wout, bout, out);
}

// Round 8
// 6868.803 us; speedup vs baseline: 2.7269x; 1.3512x over previous
//
#include <hip/hip_runtime.h>

#define B_ 16
#define T_ 1024
#define D_ 128
#define H_ 1024
#define O_ 64
#define ALPHA_ 0.1f
#define LEAK_ 0.9f
#define GRID_SCAN 256
#define FLAG_STRIDE 32   // 128B per flag line

typedef float f32x4 __attribute__((ext_vector_type(4)));

// ---------------------------------------------------------------------------
// Kernel 1: P0[b][t][j] = ALPHA * (x[b,t,:] . W_in0[j,:] + b0[j])
// written INTO the states0 region of d_out. The scan reads P0 at (b,t,j) and
// overwrites the same address with tanh(v0) -> no extra buffer needed.
// ---------------------------------------------------------------------------
__global__ __launch_bounds__(256)
void p0_kernel(const float* __restrict__ X, const float* __restrict__ Win0,
               const float* __restrict__ b0, float* __restrict__ P)
{
    __shared__ float Xs[64][68];
    __shared__ float Ws[64][68];
    const int r0 = blockIdx.x * 64;
    const int j0 = blockIdx.y * 64;
    const int tid = threadIdx.x;
    const int ty = tid >> 4, tx = tid & 15;
    float acc[4][4] = {};

    for (int kc = 0; kc < D_; kc += 64) {
        for (int i = tid; i < 64 * 16; i += 256) {   // 64 rows x 16 float4
            int row = i >> 4, c = i & 15;
            *(float4*)&Xs[row][c * 4] =
                *(const float4*)&X[(size_t)(r0 + row) * D_ + kc + c * 4];
            *(float4*)&Ws[row][c * 4] =
                *(const float4*)&Win0[(size_t)(j0 + row) * D_ + kc + c * 4];
        }
        __syncthreads();
        #pragma unroll 4
        for (int k = 0; k < 64; k += 4) {
            float4 xr[4], wv[4];
            #pragma unroll
            for (int i = 0; i < 4; ++i) {
                xr[i] = *(const float4*)&Xs[ty * 4 + i][k];
                wv[i] = *(const float4*)&Ws[tx * 4 + i][k];
            }
            #pragma unroll
            for (int i = 0; i < 4; ++i)
                #pragma unroll
                for (int j = 0; j < 4; ++j) {
                    acc[i][j] = fmaf(xr[i].x, wv[j].x, acc[i][j]);
                    acc[i][j] = fmaf(xr[i].y, wv[j].y, acc[i][j]);
                    acc[i][j] = fmaf(xr[i].z, wv[j].z, acc[i][j]);
                    acc[i][j] = fmaf(xr[i].w, wv[j].w, acc[i][j]);
                }
        }
        __syncthreads();
    }
    #pragma unroll
    for (int i = 0; i < 4; ++i) {
        size_t r = (size_t)(r0 + ty * 4 + i);
        #pragma unroll
        for (int j = 0; j < 4; ++j) {
            int jj = j0 + tx * 4 + j;
            P[r * H_ + jj] = ALPHA_ * (acc[i][j] + b0[jj]);
        }
    }
}

// ---------------------------------------------------------------------------
// Kernel 2: fused 2-layer scan — CACHED consumer loads, zero cache ops.
//
// Coherence (R7-proven):
//   * state WRITES: agent-scope relaxed atomic stores = sc1 write-through to
//     the memory-side LLC. L2 never holds dirty scan state.
//   * each state row states*[b][t][:] is written once (iter t) and consumer-
//     read once (iter t+1 / t+2). The only pre-write caching path was pval
//     (P0 read) -> pval is an sc1 BYPASS load. Hence bulk consumer loads are
//     PLAIN CACHED: a state line is first cached strictly AFTER its sc1
//     write landed in the LLC => always fresh => no inv/wbl2 ever.
//   * XCD swizzle: bg-domain d lives on XCDs {2d,2d+1} => each LLC line
//     fill is shared by 32 same-bg blocks on that XCD (FETCH 741->294MB).
//
// Round-8 change: flag publish RELEASE -> RELAXED. The RELEASE agent store
// lowers conservatively to a per-iteration buffer_wbl2 (compiler can't know
// our data stores are already write-through). Flash L2 ops measured ~6-7us
// on this chip even when clean (R0 vs R1, R5) — this was the invariant
// ~7us/iter in every round since R1. Release ordering is provided FOR FREE
// by the barrier drain: __syncthreads() forces vmcnt(0) per wave => all sc1
// data stores are LLC-acked BEFORE any thread passes; tid0's flag store
// issues strictly after => a poller observing the flag (sc1 load) observes
// all data stores. No cache op needed.
// Barrier: distributed 128B flag lines, per-bg domains (64 blocks), each
// thread polls one domain flag line.
// ---------------------------------------------------------------------------
#define LDX4(dst, p) \
    asm volatile("global_load_dwordx4 %0, %1, off" : "=v"(dst) : "v"(p))
#define LDSC(dst, p) \
    asm volatile("global_load_dword %0, %1, off sc0 sc1" : "=v"(dst) : "v"(p))
#define VMWAIT(n) asm volatile("s_waitcnt vmcnt(" #n ")" ::: "memory")
#define SB0 __builtin_amdgcn_sched_barrier(0)

#define ISSUE_AB(g) do {                                                   \
    const float* pa_ = sa + (size_t)(g) * BT;                              \
    const float* pb_ = sb + (size_t)(g) * BT;                              \
    LDX4(A[g][0], pa_);      LDX4(A[g][1], pa_ + 4);                       \
    LDX4(A[g][2], pa_ + 8);  LDX4(A[g][3], pa_ + 12);                      \
    LDX4(Bv[g][0], pb_);     LDX4(Bv[g][1], pb_ + 4);                      \
    LDX4(Bv[g][2], pb_ + 8); LDX4(Bv[g][3], pb_ + 12);                     \
} while (0)

#define ISSUE_A(g) do {                                                    \
    const float* pa_ = sa + (size_t)(g) * BT;                              \
    LDX4(A[g][0], pa_);      LDX4(A[g][1], pa_ + 4);                       \
    LDX4(A[g][2], pa_ + 8);  LDX4(A[g][3], pa_ + 12);                      \
} while (0)

#define FMA3(g) do {                                                       \
    _Pragma("unroll")                                                      \
    for (int m_ = 0; m_ < 4; ++m_) {                                       \
        _Pragma("unroll")                                                  \
        for (int c_ = 0; c_ < 4; ++c_) {                                   \
            const int kk_ = m_ * 4 + c_;                                   \
            const float xa_ = A[g][m_][c_];                                \
            const float xb_ = Bv[g][m_][c_];                               \
            _Pragma("unroll")                                              \
            for (int j_ = 0; j_ < 4; ++j_) {                               \
                ar0[(g)*4+j_] = fmaf(xa_, wr0[j_][kk_], ar0[(g)*4+j_]);    \
                ai1[(g)*4+j_] = fmaf(xa_, wi1[j_][kk_], ai1[(g)*4+j_]);    \
                ar1[(g)*4+j_] = fmaf(xb_, wr1[j_][kk_], ar1[(g)*4+j_]);    \
            }                                                              \
        }                                                                  \
    }                                                                      \
} while (0)

#define FMA2(g) do {                                                       \
    _Pragma("unroll")                                                      \
    for (int m_ = 0; m_ < 4; ++m_) {                                       \
        _Pragma("unroll")                                                  \
        for (int c_ = 0; c_ < 4; ++c_) {                                   \
            const int kk_ = m_ * 4 + c_;                                   \
            const float xa_ = A[g][m_][c_];                                \
            _Pragma("unroll")                                              \
            for (int j_ = 0; j_ < 4; ++j_) {                               \
                ar0[(g)*4+j_] = fmaf(xa_, wr0[j_][kk_], ar0[(g)*4+j_]);    \
                ai1[(g)*4+j_] = fmaf(xa_, wi1[j_][kk_], ai1[(g)*4+j_]);    \
            }                                                              \
        }                                                                  \
    }                                                                      \
} while (0)

__global__ __launch_bounds__(256, 1)
void scan_kernel(const float* __restrict__ Wr0,
                 const float* __restrict__ Wi1,
                 const float* __restrict__ Wr1,
                 const float* __restrict__ b1,
                 float* __restrict__ states0,   // pre-filled with P0
                 float* __restrict__ states1,
                 unsigned int* __restrict__ flags)
{
    const int tid  = threadIdx.x;
    // ---- XCD-aware logical id: bg-domain d -> XCDs {2d, 2d+1} ----
    // dispatch maps block -> XCD as blk % 8 (round-robin over 8 XCDs)
    const int xcd  = blockIdx.x & 7;
    const int slot = blockIdx.x >> 3;
    const int bg   = xcd >> 1;               // 4 batch-groups of 4
    const int jg   = slot * 2 + (xcd & 1);   // 64 j-groups of 16
    const int lid  = bg * 64 + jg;           // logical block id (flag index)
    const int lane = tid & 63;
    const int w    = tid >> 6;
    const int jq   = lane & 3;      // j-quad within the 16-j group
    const int kl   = lane >> 2;     // 16 k-slices per wave
    const int ks   = w * 16 + kl;   // 0..63
    const int k0   = ks << 4;       // 16-wide k slice
    const int jbase = jg * 16 + jq * 4;
    const size_t BT = (size_t)T_ * H_;

    // ---- pin weights in registers: [4 j][16 k] per matrix ----
    float wr0[4][16], wi1[4][16], wr1[4][16];
    #pragma unroll
    for (int j = 0; j < 4; ++j) {
        const float* p0 = Wr0 + (size_t)(jbase + j) * H_ + k0;
        const float* p1 = Wi1 + (size_t)(jbase + j) * H_ + k0;
        const float* p2 = Wr1 + (size_t)(jbase + j) * H_ + k0;
        #pragma unroll
        for (int m = 0; m < 4; ++m) {
            *(float4*)&wr0[j][m * 4] = ((const float4*)p0)[m];
            *(float4*)&wi1[j][m * 4] = ((const float4*)p1)[m];
            *(float4*)&wr1[j][m * 4] = ((const float4*)p2)[m];
        }
    }

    // ---- owners: tid 0..63 own layer0 outputs (4b x 16j), 64..127 layer1 ----
    const int o      = tid & 63;
    const int b_loc  = o >> 4, j_loc = o & 15;
    const int gb     = bg * 4 + b_loc;
    const int gj     = jg * 16 + j_loc;
    const int otile  = j_loc >> 2;                 // jq of this output
    const int oa     = b_loc * 4 + (j_loc & 3);    // acc index g*4+jj
    float v0 = 0.f, v1 = 0.f;
    const float b1v = b1[gj];

    __shared__ float red[3][4][4][16];   // [matvec][wave][jq][acc]

    unsigned* myflag   = flags + (size_t)lid * FLAG_STRIDE;
    // poll own bg-domain only (64 blocks); 4 threads/block share each flag
    unsigned* pollflag = flags + (size_t)(bg * 64 + (tid & 63)) * FLAG_STRIDE;

    for (int it = 0; it <= T_; ++it) {
        // early P0 load for layer0 owners — sc1 BYPASS so P0 lines are never
        // pre-cached (they'd go stale when fr overwrites them; see header).
        float pval = 0.f;
        size_t oidx0 = 0;
        if (tid < 64 && it < T_) {
            oidx0 = (size_t)gb * BT + (size_t)it * H_ + gj;
            LDSC(pval, states0 + oidx0);
        }

        float ar0[16], ai1[16], ar1[16];
        #pragma unroll
        for (int a = 0; a < 16; ++a) { ar0[a] = 0.f; ai1[a] = 0.f; ar1[a] = 0.f; }

        if (it >= 2) {
            f32x4 A[4][4], Bv[4][4];
            const float* sa = states0 + (size_t)(bg * 4) * BT + (size_t)(it - 1) * H_ + k0;
            const float* sb = states1 + (size_t)(bg * 4) * BT + (size_t)(it - 2) * H_ + k0;
            // pipeline: 3 groups in flight, peel one per FMA block.
            ISSUE_AB(0); ISSUE_AB(1); ISSUE_AB(2);
            VMWAIT(16); SB0;            // group0 landed
            FMA3(0);
            ISSUE_AB(3);
            VMWAIT(16); SB0;            // group1 landed
            FMA3(1);
            VMWAIT(8); SB0;             // group2 landed
            FMA3(2);
            VMWAIT(0); SB0;             // group3 + pval landed
            FMA3(3);
        } else if (it == 1) {
            f32x4 A[4][4];
            const float* sa = states0 + (size_t)(bg * 4) * BT + k0;   // t = 0
            ISSUE_A(0); ISSUE_A(1); ISSUE_A(2); ISSUE_A(3);
            VMWAIT(0); SB0;
            FMA2(0); FMA2(1); FMA2(2); FMA2(3);   // ar1 stays 0 (fr1[-1]=0)
        }

        // in-wave reduction over kl (lane bits 2..5)
        #pragma unroll
        for (int mask = 4; mask < 64; mask <<= 1)
            #pragma unroll
            for (int a = 0; a < 16; ++a) {
                ar0[a] += __shfl_xor(ar0[a], mask);
                ai1[a] += __shfl_xor(ai1[a], mask);
                ar1[a] += __shfl_xor(ar1[a], mask);
            }
        if (lane < 4) {                  // kl==0 lanes, one per jq
            #pragma unroll
            for (int a = 0; a < 16; ++a) {
                red[0][w][lane][a] = ar0[a];
                red[1][w][lane][a] = ai1[a];
                red[2][w][lane][a] = ar1[a];
            }
        }
        VMWAIT(0); SB0;                  // pval guaranteed resident (it==0 path)
        __syncthreads();

        if (tid < 64) {
            if (it < T_) {
                float s = red[0][0][otile][oa] + red[0][1][otile][oa]
                        + red[0][2][otile][oa] + red[0][3][otile][oa];
                v0 = LEAK_ * v0 + pval + ALPHA_ * s;
                float fr = tanhf(v0);
                // write-through to LLC (agent scope): L2 never dirty
                __hip_atomic_store(&states0[oidx0], fr, __ATOMIC_RELAXED,
                                   __HIP_MEMORY_SCOPE_AGENT);
            }
        } else if (tid < 128) {
            if (it >= 1) {
                float s1 = red[1][0][otile][oa] + red[1][1][otile][oa]
                         + red[1][2][otile][oa] + red[1][3][otile][oa];
                float s2 = red[2][0][otile][oa] + red[2][1][otile][oa]
                         + red[2][2][otile][oa] + red[2][3][otile][oa];
                v1 = LEAK_ * v1 + ALPHA_ * (s1 + s2 + b1v);
                float fr = tanhf(v1);
                __hip_atomic_store(&states1[(size_t)gb * BT + (size_t)(it - 1) * H_ + gj],
                                   fr, __ATOMIC_RELAXED, __HIP_MEMORY_SCOPE_AGENT);
            }
        }

        if (it < T_) {
            // ---- grid barrier: distributed flags, same-bg domain (64 blks) ----
            __syncthreads();   // DRAIN: every wave passes vmcnt(0) here =>
                               // all sc1 data stores are LLC-acked before
                               // any thread proceeds. This IS the release.
            const unsigned tgt = (unsigned)(it + 1);
            if (tid == 0) {
                // RELAXED publish: no buffer_wbl2 (the release-store lowering
                // was the invariant ~7us/iter flash-L2 cost). Ordering is
                // guaranteed by the barrier drain above.
                __hip_atomic_store(myflag, tgt, __ATOMIC_RELAXED,
                                   __HIP_MEMORY_SCOPE_AGENT);
            }
            // each thread polls one domain flag line (64 distinct lines)
            while (__hip_atomic_load(pollflag, __ATOMIC_RELAXED,
                                     __HIP_MEMORY_SCOPE_AGENT) < tgt)
                __builtin_amdgcn_s_sleep(2);
            __syncthreads();
            // no acquire fence: every state line is first cached AFTER its
            // sc1 write-through landed in the LLC (see header proof).
        }
    }
}

// ---------------------------------------------------------------------------
// Kernel 3: out[r][o] = states1[r,:] . W_out[o,:] + b_out[o],  r = b*T+t
// ---------------------------------------------------------------------------
__global__ __launch_bounds__(256)
void out_kernel(const float* __restrict__ S1, const float* __restrict__ Wout,
                const float* __restrict__ bout, float* __restrict__ Out)
{
    __shared__ float Ss[64][36];
    __shared__ float Ws[64][36];
    const int r0 = blockIdx.x * 64;
    const int tid = threadIdx.x;
    const int ty = tid >> 4, tx = tid & 15;
    float acc[4][4] = {};

    for (int kc = 0; kc < H_; kc += 32) {
        for (int i = tid; i < 64 * 8; i += 256) {   // 64 rows x 8 float4
            int row = i >> 3, c = i & 7;
            *(float4*)&Ss[row][c * 4] =
                *(const float4*)&S1[(size_t)(r0 + row) * H_ + kc + c * 4];
            *(float4*)&Ws[row][c * 4] =
                *(const float4*)&Wout[(size_t)row * H_ + kc + c * 4];
        }
        __syncthreads();
        #pragma unroll 2
        for (int k = 0; k < 32; k += 4) {
            float4 xr[4], wv[4];
            #pragma unroll
            for (int i = 0; i < 4; ++i) {
                xr[i] = *(const float4*)&Ss[ty * 4 + i][k];
                wv[i] = *(const float4*)&Ws[tx * 4 + i][k];
            }
            #pragma unroll
            for (int i = 0; i < 4; ++i)
                #pragma unroll
                for (int j = 0; j < 4; ++j) {
                    acc[i][j] = fmaf(xr[i].x, wv[j].x, acc[i][j]);
                    acc[i][j] = fmaf(xr[i].y, wv[j].y, acc[i][j]);
                    acc[i][j] = fmaf(xr[i].z, wv[j].z, acc[i][j]);
                    acc[i][j] = fmaf(xr[i].w, wv[j].w, acc[i][j]);
                }
        }
        __syncthreads();
    }
    #pragma unroll
    for (int i = 0; i < 4; ++i) {
        size_t r = (size_t)(r0 + ty * 4 + i);
        #pragma unroll
        for (int j = 0; j < 4; ++j) {
            int oo = tx * 4 + j;
            Out[r * O_ + oo] = acc[i][j] + bout[oo];
        }
    }
}

// ---------------------------------------------------------------------------
extern "C" void kernel_launch(void* const* d_in, const int* in_sizes, int n_in,
                              void* d_out, int out_size, void* d_ws, size_t ws_size,
                              hipStream_t stream)
{
    (void)in_sizes; (void)n_in; (void)out_size; (void)ws_size;

    const float* x    = (const float*)d_in[0];
    const float* Win0 = (const float*)d_in[1];
    const float* Wr0  = (const float*)d_in[2];
    const float* b0   = (const float*)d_in[3];
    const float* Wi1  = (const float*)d_in[4];
    const float* Wr1  = (const float*)d_in[5];
    const float* b1   = (const float*)d_in[6];
    const float* Wout = (const float*)d_in[7];
    const float* bout = (const float*)d_in[8];

    float* out     = (float*)d_out;
    float* states0 = out + (size_t)B_ * T_ * O_;
    float* states1 = states0 + (size_t)B_ * T_ * H_;

    unsigned* flags = (unsigned*)d_ws;   // 256 flags, 128B apart = 32KB

    // zero flag lines (ws is poisoned 0xAA before every call)
    hipMemsetAsync(d_ws, 0, GRID_SCAN * FLAG_STRIDE * sizeof(unsigned), stream);

    // P0 -> states0 region
    p0_kernel<<<dim3(B_ * T_ / 64, H_ / 64), 256, 0, stream>>>(x, Win0, b0, states0);

    // fused scan
    scan_kernel<<<dim3(GRID_SCAN), dim3(256), 0, stream>>>(
        Wr0, Wi1, Wr1, b1, states0, states1, flags);

    // readout
    out_kernel<<<dim3(B_ * T_ / 64), 256, 0, stream>>>(states1, Wout, bout, out);
}

// Round 9
// 4976.917 us; speedup vs baseline: 3.7635x; 1.3801x over previous
//
#include <hip/hip_runtime.h>

#define B_ 16
#define T_ 1024
#define D_ 128
#define H_ 1024
#define O_ 64
#define ALPHA_ 0.1f
#define LEAK_ 0.9f
#define GRID_SCAN 256

typedef float f32x4 __attribute__((ext_vector_type(4)));

// ---------------------------------------------------------------------------
// Kernel 1: P0[b][t][j] = ALPHA * (x[b,t,:] . W_in0[j,:] + b0[j])
// written INTO the states0 region of d_out. The scan reads P0 at (b,t,j) and
// overwrites the same address with tanh(v0) -> no extra buffer needed.
// ---------------------------------------------------------------------------
__global__ __launch_bounds__(256)
void p0_kernel(const float* __restrict__ X, const float* __restrict__ Win0,
               const float* __restrict__ b0, float* __restrict__ P)
{
    __shared__ float Xs[64][68];
    __shared__ float Ws[64][68];
    const int r0 = blockIdx.x * 64;
    const int j0 = blockIdx.y * 64;
    const int tid = threadIdx.x;
    const int ty = tid >> 4, tx = tid & 15;
    float acc[4][4] = {};

    for (int kc = 0; kc < D_; kc += 64) {
        for (int i = tid; i < 64 * 16; i += 256) {   // 64 rows x 16 float4
            int row = i >> 4, c = i & 15;
            *(float4*)&Xs[row][c * 4] =
                *(const float4*)&X[(size_t)(r0 + row) * D_ + kc + c * 4];
            *(float4*)&Ws[row][c * 4] =
                *(const float4*)&Win0[(size_t)(j0 + row) * D_ + kc + c * 4];
        }
        __syncthreads();
        #pragma unroll 4
        for (int k = 0; k < 64; k += 4) {
            float4 xr[4], wv[4];
            #pragma unroll
            for (int i = 0; i < 4; ++i) {
                xr[i] = *(const float4*)&Xs[ty * 4 + i][k];
                wv[i] = *(const float4*)&Ws[tx * 4 + i][k];
            }
            #pragma unroll
            for (int i = 0; i < 4; ++i)
                #pragma unroll
                for (int j = 0; j < 4; ++j) {
                    acc[i][j] = fmaf(xr[i].x, wv[j].x, acc[i][j]);
                    acc[i][j] = fmaf(xr[i].y, wv[j].y, acc[i][j]);
                    acc[i][j] = fmaf(xr[i].z, wv[j].z, acc[i][j]);
                    acc[i][j] = fmaf(xr[i].w, wv[j].w, acc[i][j]);
                }
        }
        __syncthreads();
    }
    #pragma unroll
    for (int i = 0; i < 4; ++i) {
        size_t r = (size_t)(r0 + ty * 4 + i);
        #pragma unroll
        for (int j = 0; j < 4; ++j) {
            int jj = j0 + tx * 4 + j;
            P[r * H_ + jj] = ALPHA_ * (acc[i][j] + b0[jj]);
        }
    }
}

// ---------------------------------------------------------------------------
// Kernel 2: fused 2-layer scan — SPLIT-FLAG PIPELINE (round 9).
//
// Coherence (R7/R8-HW-proven, unchanged):
//   * state writes: agent-scope relaxed atomic stores (sc1 write-through to
//     LLC; L2 never dirty). vmcnt-ack => LLC-visible (R8-proven).
//   * consumer state reads: plain cached loads — a state line is first
//     cached strictly AFTER its sc1 write landed (pval is sc1-bypass; no
//     other pre-write path). No fences/invalidates ever.
//   * flag publish: RELAXED sc1 store AFTER a wave-local VMWAIT(0) that
//     acks the data stores (the R8 barrier-drain argument, wave-local:
//     all fr0 owners are wave 0, all fr1 owners are wave 1).
//
// Pipeline: flag0 (fr0 ready) gates next iter's states0 loads; flag1 (fr1
// ready) gates states1 loads one iteration later (full slack). The fr1
// work (1/3 of FMAs + its tail) moves OFF the fr0 critical path:
//   top: poll flag0>=it (wave-coalesced: lane L watches dense flag[L],
//        __all exit — 4 lines/wave/round, ~16x less poll traffic)
//   A:   load sa rows + (ar0 + ai1) FMAs (A-row regs die per row),
//        reduce acc0, B1
//   tail0 (wave0): fr0 = tanh(...), sc1 store, VMWAIT(0), publish flag0
//   B:   poll flag1>=it (it>=2), load sb rows, ar1 FMAs into acc1
//        (ai1+ar1 share one accumulator — summed anyway), reduce acc1, B2
//   tail1 (wave1): fr1, sc1 store, VMWAIT(0), publish flag1
// Progress: iter it polls only iter it-1 publications (inductive, no
// circular wait). Waves 0/1 tails run on their own SIMDs.
// ---------------------------------------------------------------------------
#define LDX4(dst, p) \
    asm volatile("global_load_dwordx4 %0, %1, off" : "=v"(dst) : "v"(p))
#define LDSC(dst, p) \
    asm volatile("global_load_dword %0, %1, off sc0 sc1" : "=v"(dst) : "v"(p))
#define VMWAIT(n) asm volatile("s_waitcnt vmcnt(" #n ")" ::: "memory")
#define SB0 __builtin_amdgcn_sched_barrier(0)

// wave-coalesced poll: lane L watches dense flag line word L; __all exit.
#define POLL(ptr, tgtv) do {                                               \
    for (;;) {                                                             \
        unsigned pv_;                                                      \
        LDSC(pv_, (ptr));                                                  \
        VMWAIT(0);                                                         \
        if (__all((int)(pv_ >= (tgtv)))) break;                            \
        __builtin_amdgcn_s_sleep(1);                                       \
    }                                                                      \
    SB0;                                                                   \
} while (0)

#define FMA_A(Ar, r) do {                                                  \
    _Pragma("unroll")                                                      \
    for (int m_ = 0; m_ < 4; ++m_)                                         \
        _Pragma("unroll")                                                  \
        for (int c_ = 0; c_ < 4; ++c_) {                                   \
            const int kk_ = m_ * 4 + c_;                                   \
            const float xa_ = Ar[m_][c_];                                  \
            _Pragma("unroll")                                              \
            for (int j_ = 0; j_ < 4; ++j_) {                               \
                acc0[(r)*4+j_] = fmaf(xa_, wr0[j_][kk_], acc0[(r)*4+j_]);  \
                acc1[(r)*4+j_] = fmaf(xa_, wi1[j_][kk_], acc1[(r)*4+j_]);  \
            }                                                              \
        }                                                                  \
} while (0)

#define FMA_B(Br, r) do {                                                  \
    _Pragma("unroll")                                                      \
    for (int m_ = 0; m_ < 4; ++m_)                                         \
        _Pragma("unroll")                                                  \
        for (int c_ = 0; c_ < 4; ++c_) {                                   \
            const int kk_ = m_ * 4 + c_;                                   \
            const float xb_ = Br[m_][c_];                                  \
            _Pragma("unroll")                                              \
            for (int j_ = 0; j_ < 4; ++j_)                                 \
                acc1[(r)*4+j_] = fmaf(xb_, wr1[j_][kk_], acc1[(r)*4+j_]);  \
        }                                                                  \
} while (0)

__global__ __launch_bounds__(256, 1)
void scan_kernel(const float* __restrict__ Wr0,
                 const float* __restrict__ Wi1,
                 const float* __restrict__ Wr1,
                 const float* __restrict__ b1,
                 float* __restrict__ states0,   // pre-filled with P0
                 float* __restrict__ states1,
                 unsigned int* __restrict__ flags)
{
    const int tid  = threadIdx.x;
    // XCD-aware logical id: bg-domain d -> XCDs {2d, 2d+1} (blk%8 = XCD)
    const int xcd  = blockIdx.x & 7;
    const int slot = blockIdx.x >> 3;
    const int bg   = xcd >> 1;               // 4 batch-groups of 4
    const int jg   = slot * 2 + (xcd & 1);   // 64 j-groups of 16
    const int lane = tid & 63;
    const int w    = tid >> 6;
    const int jq   = lane & 3;      // j-quad within the 16-j group
    const int kl   = lane >> 2;     // 16 k-slices per wave
    const int ks   = w * 16 + kl;   // 0..63
    const int k0   = ks << 4;       // 16-wide k slice
    const int jbase = jg * 16 + jq * 4;
    const size_t BT = (size_t)T_ * H_;

    // ---- pin weights in registers: [4 j][16 k] per matrix ----
    float wr0[4][16], wi1[4][16], wr1[4][16];
    #pragma unroll
    for (int j = 0; j < 4; ++j) {
        const float* p0 = Wr0 + (size_t)(jbase + j) * H_ + k0;
        const float* p1 = Wi1 + (size_t)(jbase + j) * H_ + k0;
        const float* p2 = Wr1 + (size_t)(jbase + j) * H_ + k0;
        #pragma unroll
        for (int m = 0; m < 4; ++m) {
            *(float4*)&wr0[j][m * 4] = ((const float4*)p0)[m];
            *(float4*)&wi1[j][m * 4] = ((const float4*)p1)[m];
            *(float4*)&wr1[j][m * 4] = ((const float4*)p2)[m];
        }
    }

    // ---- owners: wave0 lanes own fr0 outputs, wave1 lanes own fr1 ----
    const int o      = tid & 63;
    const int b_loc  = o >> 4, j_loc = o & 15;
    const int gb     = bg * 4 + b_loc;
    const int gj     = jg * 16 + j_loc;
    const int otile  = j_loc >> 2;                 // jq of this output
    const int oa     = b_loc * 4 + (j_loc & 3);    // acc index r*4+jj
    float v0 = 0.f, v1 = 0.f;
    const float b1v = b1[gj];

    __shared__ float red[2][4][4][16];   // [acc][wave][jq][val]

    unsigned* flag0 = flags;             // dense: flag0[bg*64 + jg]
    unsigned* flag1 = flags + 256;       // dense: flag1[bg*64 + jg]
    unsigned* myf0  = flag0 + bg * 64 + jg;
    unsigned* myf1  = flag1 + bg * 64 + jg;
    const unsigned* pf0 = flag0 + bg * 64 + lane;
    const unsigned* pf1 = flag1 + bg * 64 + lane;

    // ---- prologue (t = 0): fr0[0] = tanh(P0[b][0][j]); wave-local ----
    if (tid < 64) {
        size_t oidx = (size_t)gb * BT + gj;
        float pv;
        LDSC(pv, states0 + oidx);
        VMWAIT(0); SB0;
        v0 = pv;                          // v0 = 0.9*0 + P0 + 0.1*0
        float fr = tanhf(v0);
        __hip_atomic_store(&states0[oidx], fr, __ATOMIC_RELAXED,
                           __HIP_MEMORY_SCOPE_AGENT);
        VMWAIT(0); SB0;                   // fr0 stores LLC-acked
        if (tid == 0)
            __hip_atomic_store(myf0, 1u, __ATOMIC_RELAXED,
                               __HIP_MEMORY_SCOPE_AGENT);
    }

    for (int it = 1; it <= T_; ++it) {
        const unsigned tgt = (unsigned)it;

        // ---- top: poll flag0 >= it (gates states0[it-1] reads) ----
        POLL(pf0, tgt);

        float acc0[16], acc1[16];
        #pragma unroll
        for (int a = 0; a < 16; ++a) { acc0[a] = 0.f; acc1[a] = 0.f; }

        // ---- phase A: sa rows; ar0 + ai1 FMAs (A rows die per row) ----
        const float* sa = states0 + (size_t)(bg * 4) * BT
                        + (size_t)(it - 1) * H_ + k0;
        f32x4 A0[4], A1[4], A2[4], A3[4];
        LDX4(A0[0], sa);          LDX4(A0[1], sa + 4);
        LDX4(A0[2], sa + 8);      LDX4(A0[3], sa + 12);
        LDX4(A1[0], sa + BT);     LDX4(A1[1], sa + BT + 4);
        LDX4(A1[2], sa + BT + 8); LDX4(A1[3], sa + BT + 12);
        LDX4(A2[0], sa + 2*BT);     LDX4(A2[1], sa + 2*BT + 4);
        LDX4(A2[2], sa + 2*BT + 8); LDX4(A2[3], sa + 2*BT + 12);
        LDX4(A3[0], sa + 3*BT);     LDX4(A3[1], sa + 3*BT + 4);
        LDX4(A3[2], sa + 3*BT + 8); LDX4(A3[3], sa + 3*BT + 12);
        // pval (sc1 bypass), wave0 only, issued LAST so counted waits below
        // remain valid for all waves (wave0: 17 ops, others: 16).
        float pval = 0.f;
        size_t oidx0 = 0;
        if (tid < 64) {
            const int tp = (it < T_) ? it : (T_ - 1);   // clamp; unused @T_
            oidx0 = (size_t)gb * BT + (size_t)tp * H_ + gj;
            LDSC(pval, states0 + oidx0);
        }
        VMWAIT(12); SB0;  FMA_A(A0, 0);
        VMWAIT(8);  SB0;  FMA_A(A1, 1);
        VMWAIT(4);  SB0;  FMA_A(A2, 2);
        VMWAIT(0);  SB0;  FMA_A(A3, 3);   // also drains pval

        // reduce acc0 over kl (lane bits 2..5)
        #pragma unroll
        for (int mask = 4; mask < 64; mask <<= 1)
            #pragma unroll
            for (int a = 0; a < 16; ++a)
                acc0[a] += __shfl_xor(acc0[a], mask);
        if (lane < 4)
            #pragma unroll
            for (int a = 0; a < 16; ++a)
                red[0][w][lane][a] = acc0[a];
        __syncthreads();                  // B1

        // ---- wave0 tail: fr0 + flag0 publish (wave-local ack) ----
        if (tid < 64 && it < T_) {
            float s = red[0][0][otile][oa] + red[0][1][otile][oa]
                    + red[0][2][otile][oa] + red[0][3][otile][oa];
            v0 = LEAK_ * v0 + pval + ALPHA_ * s;
            float fr = tanhf(v0);
            __hip_atomic_store(&states0[oidx0], fr, __ATOMIC_RELAXED,
                               __HIP_MEMORY_SCOPE_AGENT);
            VMWAIT(0); SB0;               // fr0 stores LLC-acked (wave0 only)
            if (tid == 0)
                __hip_atomic_store(myf0, (unsigned)(it + 1), __ATOMIC_RELAXED,
                                   __HIP_MEMORY_SCOPE_AGENT);
        }

        // ---- phase B: sb rows (gated by flag1, one iter of slack); ar1 ----
        if (it >= 2) {
            POLL(pf1, tgt);               // flag1 >= it: states1[it-2] ready
            const float* sb = states1 + (size_t)(bg * 4) * BT
                            + (size_t)(it - 2) * H_ + k0;
            f32x4 B0[4], B1r[4], B2r[4], B3r[4];
            LDX4(B0[0], sb);          LDX4(B0[1], sb + 4);
            LDX4(B0[2], sb + 8);      LDX4(B0[3], sb + 12);
            LDX4(B1r[0], sb + BT);     LDX4(B1r[1], sb + BT + 4);
            LDX4(B1r[2], sb + BT + 8); LDX4(B1r[3], sb + BT + 12);
            LDX4(B2r[0], sb + 2*BT);     LDX4(B2r[1], sb + 2*BT + 4);
            LDX4(B2r[2], sb + 2*BT + 8); LDX4(B2r[3], sb + 2*BT + 12);
            LDX4(B3r[0], sb + 3*BT);     LDX4(B3r[1], sb + 3*BT + 4);
            LDX4(B3r[2], sb + 3*BT + 8); LDX4(B3r[3], sb + 3*BT + 12);
            // wave0 may carry its flag0 store (oldest) -> counts still valid
            VMWAIT(12); SB0;  FMA_B(B0, 0);
            VMWAIT(8);  SB0;  FMA_B(B1r, 1);
            VMWAIT(4);  SB0;  FMA_B(B2r, 2);
            VMWAIT(0);  SB0;  FMA_B(B3r, 3);
        }

        // reduce acc1 (ai1 + ar1 combined)
        #pragma unroll
        for (int mask = 4; mask < 64; mask <<= 1)
            #pragma unroll
            for (int a = 0; a < 16; ++a)
                acc1[a] += __shfl_xor(acc1[a], mask);
        if (lane < 4)
            #pragma unroll
            for (int a = 0; a < 16; ++a)
                red[1][w][lane][a] = acc1[a];
        __syncthreads();                  // B2

        // ---- wave1 tail: fr1 (time it-1) + flag1 publish ----
        if (tid >= 64 && tid < 128) {
            float s = red[1][0][otile][oa] + red[1][1][otile][oa]
                    + red[1][2][otile][oa] + red[1][3][otile][oa];
            v1 = LEAK_ * v1 + ALPHA_ * (s + b1v);
            float fr = tanhf(v1);
            __hip_atomic_store(&states1[(size_t)gb * BT + (size_t)(it - 1) * H_ + gj],
                               fr, __ATOMIC_RELAXED, __HIP_MEMORY_SCOPE_AGENT);
            VMWAIT(0); SB0;               // fr1 stores LLC-acked (wave1 only)
            if (tid == 64)
                __hip_atomic_store(myf1, (unsigned)(it + 1), __ATOMIC_RELAXED,
                                   __HIP_MEMORY_SCOPE_AGENT);
        }
        // no trailing barrier: next phase A writes red[0] only after B1(it+1),
        // which wave1 reaches after its tail; red[1] next written after the
        // next B1 as well. Waves 2,3 race ahead safely.
    }
}

// ---------------------------------------------------------------------------
// Kernel 3: out[r][o] = states1[r,:] . W_out[o,:] + b_out[o],  r = b*T+t
// ---------------------------------------------------------------------------
__global__ __launch_bounds__(256)
void out_kernel(const float* __restrict__ S1, const float* __restrict__ Wout,
                const float* __restrict__ bout, float* __restrict__ Out)
{
    __shared__ float Ss[64][36];
    __shared__ float Ws[64][36];
    const int r0 = blockIdx.x * 64;
    const int tid = threadIdx.x;
    const int ty = tid >> 4, tx = tid & 15;
    float acc[4][4] = {};

    for (int kc = 0; kc < H_; kc += 32) {
        for (int i = tid; i < 64 * 8; i += 256) {   // 64 rows x 8 float4
            int row = i >> 3, c = i & 7;
            *(float4*)&Ss[row][c * 4] =
                *(const float4*)&S1[(size_t)(r0 + row) * H_ + kc + c * 4];
            *(float4*)&Ws[row][c * 4] =
                *(const float4*)&Wout[(size_t)row * H_ + kc + c * 4];
        }
        __syncthreads();
        #pragma unroll 2
        for (int k = 0; k < 32; k += 4) {
            float4 xr[4], wv[4];
            #pragma unroll
            for (int i = 0; i < 4; ++i) {
                xr[i] = *(const float4*)&Ss[ty * 4 + i][k];
                wv[i] = *(const float4*)&Ws[tx * 4 + i][k];
            }
            #pragma unroll
            for (int i = 0; i < 4; ++i)
                #pragma unroll
                for (int j = 0; j < 4; ++j) {
                    acc[i][j] = fmaf(xr[i].x, wv[j].x, acc[i][j]);
                    acc[i][j] = fmaf(xr[i].y, wv[j].y, acc[i][j]);
                    acc[i][j] = fmaf(xr[i].z, wv[j].z, acc[i][j]);
                    acc[i][j] = fmaf(xr[i].w, wv[j].w, acc[i][j]);
                }
        }
        __syncthreads();
    }
    #pragma unroll
    for (int i = 0; i < 4; ++i) {
        size_t r = (size_t)(r0 + ty * 4 + i);
        #pragma unroll
        for (int j = 0; j < 4; ++j) {
            int oo = tx * 4 + j;
            Out[r * O_ + oo] = acc[i][j] + bout[oo];
        }
    }
}

// ---------------------------------------------------------------------------
extern "C" void kernel_launch(void* const* d_in, const int* in_sizes, int n_in,
                              void* d_out, int out_size, void* d_ws, size_t ws_size,
                              hipStream_t stream)
{
    (void)in_sizes; (void)n_in; (void)out_size; (void)ws_size;

    const float* x    = (const float*)d_in[0];
    const float* Win0 = (const float*)d_in[1];
    const float* Wr0  = (const float*)d_in[2];
    const float* b0   = (const float*)d_in[3];
    const float* Wi1  = (const float*)d_in[4];
    const float* Wr1  = (const float*)d_in[5];
    const float* b1   = (const float*)d_in[6];
    const float* Wout = (const float*)d_in[7];
    const float* bout = (const float*)d_in[8];

    float* out     = (float*)d_out;
    float* states0 = out + (size_t)B_ * T_ * O_;
    float* states1 = states0 + (size_t)B_ * T_ * H_;

    unsigned* flags = (unsigned*)d_ws;   // dense: flag0[256] ++ flag1[256]

    // zero flag words (ws is poisoned 0xAA before every call)
    hipMemsetAsync(d_ws, 0, 512 * sizeof(unsigned), stream);

    // P0 -> states0 region
    p0_kernel<<<dim3(B_ * T_ / 64, H_ / 64), 256, 0, stream>>>(x, Win0, b0, states0);

    // fused scan
    scan_kernel<<<dim3(GRID_SCAN), dim3(256), 0, stream>>>(
        Wr0, Wi1, Wr1, b1, states0, states1, flags);

    // readout
    out_kernel<<<dim3(B_ * T_ / 64), 256, 0, stream>>>(states1, Wout, bout, out);
}